// Round 15
// baseline (249.932 us; speedup 1.0000x reference)
//
#include <hip/hip_runtime.h>

#define BN_EPS 1e-5f
#define NBUF 64   // spread buffers for stat atomics

typedef float        f32x4 __attribute__((ext_vector_type(4)));
typedef float        f32x2 __attribute__((ext_vector_type(2)));
typedef unsigned int u32x2 __attribute__((ext_vector_type(2)));
typedef unsigned int u32x4 __attribute__((ext_vector_type(4)));

__device__ inline unsigned pack_bf16(float a, float b) {
    unsigned ua = __float_as_uint(a);
    unsigned ub = __float_as_uint(b);
    ua = (ua + 0x7fffu + ((ua >> 16) & 1u)) >> 16;
    ub = (ub + 0x7fffu + ((ub >> 16) & 1u)) >> 16;
    return ua | (ub << 16);
}
__device__ inline float bf_lo(unsigned u) { return __uint_as_float(u << 16); }
__device__ inline float bf_hi(unsigned u) { return __uint_as_float(u & 0xffff0000u); }

// ---------------------------------------------------------------------------
// Cast fp32 -> packed bf16 (RNE). One thread = 4 floats -> 2 uints.
// ---------------------------------------------------------------------------
__global__ void __launch_bounds__(256) cast_bf16_kernel(
    const f32x4* __restrict__ in, u32x2* __restrict__ out, int n4)
{
    const int t = blockIdx.x * 256 + threadIdx.x;
    if (t >= n4) return;
    const f32x4 v = in[t];
    u32x2 r;
    r.x = pack_bf16(v.x, v.y);
    r.y = pack_bf16(v.z, v.w);
    out[t] = r;
}

// ---------------------------------------------------------------------------
// Stage 0 (round-8 proven body + bf16-packed y0, 84 VGPR, ~121us floor).
// idx: PLAIN coalesced global->LDS staging, stride-27 read.
// Gathers: all 27 in flight, agent-scope relaxed (L1 bypass, L2-resident 4MB).
// W: LDS broadcast. y0 packed bf16 (8 u32/node = 16MB).
// ---------------------------------------------------------------------------
__global__ void __launch_bounds__(256) conv0_kernel(
    const unsigned long long* __restrict__ xb, const int* __restrict__ neigh,
    const float* __restrict__ W, unsigned* __restrict__ y,
    float* __restrict__ stats)
{
    __shared__ int   idxlds[256 * 27];
    __shared__ float Wlds[27 * 4 * 16];

    for (int i = threadIdx.x; i < 27 * 4 * 16; i += 256) Wlds[i] = W[i];
    {
        const size_t base = (size_t)blockIdx.x * (256 * 27);
        for (int i = threadIdx.x; i < 256 * 27; i += 256)
            idxlds[i] = neigh[base + i];
    }
    __syncthreads();

    const int node = blockIdx.x * 256 + threadIdx.x;

    unsigned long long xr[27];
#pragma unroll
    for (int j = 0; j < 27; ++j) {
        const int nb = idxlds[threadIdx.x * 27 + j];
        xr[j] = __hip_atomic_load(xb + nb, __ATOMIC_RELAXED,
                                  __HIP_MEMORY_SCOPE_AGENT);
    }

    float acc[16];
#pragma unroll
    for (int c = 0; c < 16; ++c) acc[c] = 0.f;

#pragma unroll
    for (int j = 0; j < 27; ++j) {
        const unsigned lo = (unsigned)xr[j];
        const unsigned hi = (unsigned)(xr[j] >> 32);
        float xv[4];
        xv[0] = bf_lo(lo); xv[1] = bf_hi(lo);
        xv[2] = bf_lo(hi); xv[3] = bf_hi(hi);
#pragma unroll
        for (int kk = 0; kk < 4; ++kk) {
            const f32x4* wv = (const f32x4*)&Wlds[(j * 4 + kk) * 16];
#pragma unroll
            for (int c4 = 0; c4 < 4; ++c4) {
                const f32x4 w = wv[c4];
                acc[c4 * 4 + 0] = fmaf(xv[kk], w.x, acc[c4 * 4 + 0]);
                acc[c4 * 4 + 1] = fmaf(xv[kk], w.y, acc[c4 * 4 + 1]);
                acc[c4 * 4 + 2] = fmaf(xv[kk], w.z, acc[c4 * 4 + 2]);
                acc[c4 * 4 + 3] = fmaf(xv[kk], w.w, acc[c4 * 4 + 3]);
            }
        }
    }

    {
        unsigned* yr = y + (size_t)node * 8;
        u32x4 w0, w1;
        w0.x = pack_bf16(acc[0],  acc[1]);   w0.y = pack_bf16(acc[2],  acc[3]);
        w0.z = pack_bf16(acc[4],  acc[5]);   w0.w = pack_bf16(acc[6],  acc[7]);
        w1.x = pack_bf16(acc[8],  acc[9]);   w1.y = pack_bf16(acc[10], acc[11]);
        w1.z = pack_bf16(acc[12], acc[13]);  w1.w = pack_bf16(acc[14], acc[15]);
        __builtin_nontemporal_store(w0, (u32x4*)yr);
        __builtin_nontemporal_store(w1, (u32x4*)(yr + 4));
    }

    float* buf = stats + (blockIdx.x & (NBUF - 1)) * (2 * 16);
#pragma unroll
    for (int c = 0; c < 16; ++c) {
        float v = acc[c];
        float q = v * v;
#pragma unroll
        for (int off = 32; off > 0; off >>= 1) {
            v += __shfl_xor(v, off, 64);
            q += __shfl_xor(q, off, 64);
        }
        if ((threadIdx.x & 63) == 0) {
            atomicAdd(&buf[c], v);
            atomicAdd(&buf[16 + c], q);
        }
    }
}

// ---------------------------------------------------------------------------
// Stage-0 pool-finalize from bf16 y0: BN fold + affine + ReLU + maxpool.
// ---------------------------------------------------------------------------
__global__ void __launch_bounds__(256) pool_fin0_kernel(
    const unsigned* __restrict__ y, const float* __restrict__ stats,
    const float* __restrict__ gamma, const float* __restrict__ beta,
    unsigned* __restrict__ xout, float invN, int total2)
{
    __shared__ float ss[32];
    if (threadIdx.x < 16) {
        const int c = threadIdx.x;
        float s = 0.f, q = 0.f;
        for (int b = 0; b < NBUF; ++b) {
            s += stats[b * 32 + c];
            q += stats[b * 32 + 16 + c];
        }
        const float mean = s * invN;
        const float var  = fmaf(-mean, mean, q * invN);
        const float sc   = gamma[c] * rsqrtf(var + BN_EPS);
        ss[c]      = sc;
        ss[16 + c] = fmaf(-mean, sc, beta[c]);
    }
    __syncthreads();

    const int t = blockIdx.x * 256 + threadIdx.x;
    if (t >= total2) return;
    const int p    = t >> 3;
    const int pair = t & 7;
    const int c2 = pair * 2;
    const float sc0 = ss[c2],     sh0 = ss[16 + c2];
    const float sc1 = ss[c2 + 1], sh1 = ss[16 + c2 + 1];
    const unsigned* yr = y + (size_t)p * 64 + pair;
    float m0 = -3.4e38f, m1 = -3.4e38f;
#pragma unroll
    for (int i = 0; i < 8; ++i) {
        const unsigned u = __builtin_nontemporal_load(yr + i * 8);
        m0 = fmaxf(m0, fmaf(bf_lo(u), sc0, sh0));
        m1 = fmaxf(m1, fmaf(bf_hi(u), sc1, sh1));
    }
    m0 = fmaxf(m0, 0.f);
    m1 = fmaxf(m1, 0.f);
    xout[t] = pack_bf16(m0, m1);
}

// ---------------------------------------------------------------------------
// Stage 1 (round-8 proven 2-pass shape + bf16-packed y1): W tile 16 in LDS,
// grid (N5/256, 2), plain idx preload, GRP=3. y1: 8 u32 per (node, half).
// ---------------------------------------------------------------------------
__global__ void __launch_bounds__(256) conv1_kernel(
    const u32x4* __restrict__ xb, const int* __restrict__ neigh,
    const float* __restrict__ W, unsigned* __restrict__ y,
    float* __restrict__ stats)
{
    __shared__ float Wlds[27 * 16 * 16];
    const int cobase = blockIdx.y * 16;

    for (int i = threadIdx.x; i < 27 * 16 * 16; i += 256) {
        int k = i >> 4, c = i & 15;
        Wlds[i] = W[k * 32 + cobase + c];
    }
    __syncthreads();

    const int node = blockIdx.x * 256 + threadIdx.x;
    const int* nrow = neigh + (size_t)node * 27;

    int idx[27];
#pragma unroll
    for (int j = 0; j < 27; ++j) idx[j] = nrow[j];

    float acc[16];
#pragma unroll
    for (int c = 0; c < 16; ++c) acc[c] = 0.f;

#pragma unroll 1
    for (int g = 0; g < 27; g += 3) {
        u32x4 xa[3], xc[3];
#pragma unroll
        for (int u = 0; u < 3; ++u) {
            const size_t r = (size_t)idx[g + u] * 2;
            xa[u] = xb[r];
            xc[u] = xb[r + 1];
        }
#pragma unroll
        for (int u = 0; u < 3; ++u) {
            const int j = g + u;
            float xv[16];
            xv[0]  = bf_lo(xa[u].x); xv[1]  = bf_hi(xa[u].x);
            xv[2]  = bf_lo(xa[u].y); xv[3]  = bf_hi(xa[u].y);
            xv[4]  = bf_lo(xa[u].z); xv[5]  = bf_hi(xa[u].z);
            xv[6]  = bf_lo(xa[u].w); xv[7]  = bf_hi(xa[u].w);
            xv[8]  = bf_lo(xc[u].x); xv[9]  = bf_hi(xc[u].x);
            xv[10] = bf_lo(xc[u].y); xv[11] = bf_hi(xc[u].y);
            xv[12] = bf_lo(xc[u].z); xv[13] = bf_hi(xc[u].z);
            xv[14] = bf_lo(xc[u].w); xv[15] = bf_hi(xc[u].w);
#pragma unroll
            for (int k = 0; k < 16; ++k) {
                const f32x4* wv = (const f32x4*)&Wlds[(j * 16 + k) * 16];
#pragma unroll
                for (int c4 = 0; c4 < 4; ++c4) {
                    const f32x4 w = wv[c4];
                    acc[c4 * 4 + 0] = fmaf(xv[k], w.x, acc[c4 * 4 + 0]);
                    acc[c4 * 4 + 1] = fmaf(xv[k], w.y, acc[c4 * 4 + 1]);
                    acc[c4 * 4 + 2] = fmaf(xv[k], w.z, acc[c4 * 4 + 2]);
                    acc[c4 * 4 + 3] = fmaf(xv[k], w.w, acc[c4 * 4 + 3]);
                }
            }
        }
    }

    // y1 packed bf16: 8 u32 at node*16 + half*8
    {
        unsigned* yr = y + (size_t)node * 16 + (cobase >> 1);
        u32x4 w0, w1;
        w0.x = pack_bf16(acc[0],  acc[1]);   w0.y = pack_bf16(acc[2],  acc[3]);
        w0.z = pack_bf16(acc[4],  acc[5]);   w0.w = pack_bf16(acc[6],  acc[7]);
        w1.x = pack_bf16(acc[8],  acc[9]);   w1.y = pack_bf16(acc[10], acc[11]);
        w1.z = pack_bf16(acc[12], acc[13]);  w1.w = pack_bf16(acc[14], acc[15]);
        __builtin_nontemporal_store(w0, (u32x4*)yr);
        __builtin_nontemporal_store(w1, (u32x4*)(yr + 4));
    }

    float* buf = stats + (blockIdx.x & (NBUF - 1)) * (2 * 32);
#pragma unroll
    for (int c = 0; c < 16; ++c) {
        float v = acc[c];
        float q = v * v;
#pragma unroll
        for (int off = 32; off > 0; off >>= 1) {
            v += __shfl_xor(v, off, 64);
            q += __shfl_xor(q, off, 64);
        }
        if ((threadIdx.x & 63) == 0) {
            atomicAdd(&buf[cobase + c], v);
            atomicAdd(&buf[32 + cobase + c], q);
        }
    }
}

// ---------------------------------------------------------------------------
// Stage-1 pool-finalize from bf16 y1 (16 u32 per node).
// thread t -> (parent p, channel pair): p = t>>4, pair = t&15.
// ---------------------------------------------------------------------------
__global__ void __launch_bounds__(256) pool_fin1_kernel(
    const unsigned* __restrict__ y, const float* __restrict__ stats,
    const float* __restrict__ gamma, const float* __restrict__ beta,
    unsigned* __restrict__ xout, float invN, int total2)
{
    __shared__ float ss[64];
    if (threadIdx.x < 32) {
        const int c = threadIdx.x;
        float s = 0.f, q = 0.f;
        for (int b = 0; b < NBUF; ++b) {
            s += stats[b * 64 + c];
            q += stats[b * 64 + 32 + c];
        }
        const float mean = s * invN;
        const float var  = fmaf(-mean, mean, q * invN);
        const float sc   = gamma[c] * rsqrtf(var + BN_EPS);
        ss[c]      = sc;
        ss[32 + c] = fmaf(-mean, sc, beta[c]);
    }
    __syncthreads();

    const int t = blockIdx.x * 256 + threadIdx.x;
    if (t >= total2) return;
    const int p    = t >> 4;
    const int pair = t & 15;
    const int c2 = pair * 2;
    const float sc0 = ss[c2],     sh0 = ss[32 + c2];
    const float sc1 = ss[c2 + 1], sh1 = ss[32 + c2 + 1];
    const unsigned* yr = y + (size_t)p * 128 + pair;   // 8 siblings * 16 u32
    float m0 = -3.4e38f, m1 = -3.4e38f;
#pragma unroll
    for (int i = 0; i < 8; ++i) {
        const unsigned u = __builtin_nontemporal_load(yr + i * 16);
        m0 = fmaxf(m0, fmaf(bf_lo(u), sc0, sh0));
        m1 = fmaxf(m1, fmaf(bf_hi(u), sc1, sh1));
    }
    m0 = fmaxf(m0, 0.f);
    m1 = fmaxf(m1, 0.f);
    xout[t] = pack_bf16(m0, m1);
}

// ---------------------------------------------------------------------------
// Stage 2 (round-8 shape + bf16-packed y2): thread-per-(node, channel-quad),
// 16 nodes/block, idx in LDS, W fp32 from L2. y2: 2 u32 per thread.
// ---------------------------------------------------------------------------
__global__ void __launch_bounds__(256) conv2_kernel(
    const u32x4* __restrict__ xb, const int* __restrict__ neigh,
    const float* __restrict__ W, unsigned* __restrict__ y,
    float* __restrict__ stats)
{
    __shared__ int idxlds[16 * 27];
    const int nbase = blockIdx.x * 16;
    for (int i = threadIdx.x; i < 16 * 27; i += 256) {
        int n = i / 27, j = i - n * 27;
        idxlds[i] = neigh[(size_t)(nbase + n) * 27 + j];
    }
    __syncthreads();

    const int ln = threadIdx.x >> 4;
    const int c4 = threadIdx.x & 15;
    const int node = nbase + ln;

    f32x4 acc = { 0.f, 0.f, 0.f, 0.f };

#pragma unroll 1
    for (int j = 0; j < 27; ++j) {
        const int nb = idxlds[ln * 27 + j];
        const u32x4* xr = xb + (size_t)nb * 4;
        u32x4 xq[4];
#pragma unroll
        for (int q = 0; q < 4; ++q) xq[q] = xr[q];
#pragma unroll
        for (int q = 0; q < 4; ++q) {
            float xv[8];
            xv[0] = bf_lo(xq[q].x); xv[1] = bf_hi(xq[q].x);
            xv[2] = bf_lo(xq[q].y); xv[3] = bf_hi(xq[q].y);
            xv[4] = bf_lo(xq[q].z); xv[5] = bf_hi(xq[q].z);
            xv[6] = bf_lo(xq[q].w); xv[7] = bf_hi(xq[q].w);
#pragma unroll
            for (int h = 0; h < 8; ++h) {
                const int k = q * 8 + h;
                const f32x4 w = *(const f32x4*)(W + ((size_t)j * 32 + k) * 64 + c4 * 4);
                acc.x = fmaf(xv[h], w.x, acc.x);
                acc.y = fmaf(xv[h], w.y, acc.y);
                acc.z = fmaf(xv[h], w.z, acc.z);
                acc.w = fmaf(xv[h], w.w, acc.w);
            }
        }
    }

    {
        u32x2 w;
        w.x = pack_bf16(acc.x, acc.y);
        w.y = pack_bf16(acc.z, acc.w);
        __builtin_nontemporal_store(w, (u32x2*)(y + (size_t)node * 32 + c4 * 2));
    }

    float sx = acc.x, sy = acc.y, sz = acc.z, sw = acc.w;
    float qx = acc.x * acc.x, qy = acc.y * acc.y, qz = acc.z * acc.z, qw = acc.w * acc.w;
#pragma unroll
    for (int off = 16; off <= 32; off <<= 1) {
        sx += __shfl_xor(sx, off, 64);  sy += __shfl_xor(sy, off, 64);
        sz += __shfl_xor(sz, off, 64);  sw += __shfl_xor(sw, off, 64);
        qx += __shfl_xor(qx, off, 64);  qy += __shfl_xor(qy, off, 64);
        qz += __shfl_xor(qz, off, 64);  qw += __shfl_xor(qw, off, 64);
    }
    if ((threadIdx.x & 63) < 16) {
        float* buf = stats + (blockIdx.x & (NBUF - 1)) * (2 * 64);
        atomicAdd(&buf[c4 * 4 + 0], sx);
        atomicAdd(&buf[c4 * 4 + 1], sy);
        atomicAdd(&buf[c4 * 4 + 2], sz);
        atomicAdd(&buf[c4 * 4 + 3], sw);
        atomicAdd(&buf[64 + c4 * 4 + 0], qx);
        atomicAdd(&buf[64 + c4 * 4 + 1], qy);
        atomicAdd(&buf[64 + c4 * 4 + 2], qz);
        atomicAdd(&buf[64 + c4 * 4 + 3], qw);
    }
}

// ---------------------------------------------------------------------------
// Stage-2 epilogue from bf16 y2: BN-finalize + affine + ReLU + maxpool +
// octree2voxel scatter. vox = arange(N3) covers all outputs -> no memset.
// ---------------------------------------------------------------------------
__global__ void __launch_bounds__(256) pool_fin2_scatter_kernel(
    const unsigned* __restrict__ y, const float* __restrict__ stats,
    const float* __restrict__ gamma, const float* __restrict__ beta,
    const int* __restrict__ vox, float* __restrict__ out, float invN)
{
    __shared__ float ss[128];
    if (threadIdx.x < 64) {
        const int c = threadIdx.x;
        float s = 0.f, q = 0.f;
        for (int b = 0; b < NBUF; ++b) {
            s += stats[b * 128 + c];
            q += stats[b * 128 + 64 + c];
        }
        const float mean = s * invN;
        const float var  = fmaf(-mean, mean, q * invN);
        const float sc   = gamma[c] * rsqrtf(var + BN_EPS);
        ss[c]      = sc;
        ss[64 + c] = fmaf(-mean, sc, beta[c]);
    }
    __syncthreads();

    const int t = blockIdx.x * 256 + threadIdx.x;   // N3*32 = 32768 threads
    const int p    = t >> 5;
    const int pair = t & 31;
    const int c2 = pair * 2;
    const float sc0 = ss[c2],     sh0 = ss[64 + c2];
    const float sc1 = ss[c2 + 1], sh1 = ss[64 + c2 + 1];
    const unsigned* yr = y + (size_t)p * 256 + pair;   // 8 siblings * 32 u32
    float m0 = -3.4e38f, m1 = -3.4e38f;
#pragma unroll
    for (int i = 0; i < 8; ++i) {
        const unsigned u = __builtin_nontemporal_load(yr + i * 32);
        m0 = fmaxf(m0, fmaf(bf_lo(u), sc0, sh0));
        m1 = fmaxf(m1, fmaf(bf_hi(u), sc1, sh1));
    }
    m0 = fmaxf(m0, 0.f);
    m1 = fmaxf(m1, 0.f);

    const int r = vox[p];
    const int base = ((r >> 9) << 15) + (r & 511);
    out[base + (c2 << 9)]       = m0;
    out[base + ((c2 + 1) << 9)] = m1;
}

extern "C" void kernel_launch(void* const* d_in, const int* in_sizes, int n_in,
                              void* d_out, int out_size, void* d_ws, size_t ws_size,
                              hipStream_t stream)
{
    const float* data = (const float*)d_in[0];
    const float* W0   = (const float*)d_in[1];
    const float* g0   = (const float*)d_in[2];
    const float* b0   = (const float*)d_in[3];
    const float* W1   = (const float*)d_in[4];
    const float* g1   = (const float*)d_in[5];
    const float* b1   = (const float*)d_in[6];
    const float* W2   = (const float*)d_in[7];
    const float* g2   = (const float*)d_in[8];
    const float* b2   = (const float*)d_in[9];
    const int* neigh0 = (const int*)d_in[10];
    const int* neigh1 = (const int*)d_in[11];
    const int* neigh2 = (const int*)d_in[12];
    const int* vox    = (const int*)d_in[13];

    const int N6 = 524288, N5 = 65536, N4 = 8192, N3 = 1024;

    float* ws = (float*)d_ws;
    const size_t off_y0  = 0;                                 // N6*8  (bf16 y0)
    const size_t off_xb1 = off_y0 + (size_t)N6 * 8;           // N5*8  (bf16 x1)
    const size_t off_y1  = off_xb1 + (size_t)N5 * 8;          // N5*16 (bf16 y1)
    const size_t off_xb0 = off_y1;                            // N6*2 = N5*16 (alias)
    const size_t off_xb2 = off_y1 + (size_t)N5 * 16;          // N4*16 (bf16 x2)
    const size_t off_y2  = off_xb2 + (size_t)N4 * 16;         // N4*32 (bf16 y2)
    const size_t off_st0 = off_y2 + (size_t)N4 * 32;          // NBUF*2*16
    const size_t off_st1 = off_st0 + NBUF * 2 * 16;           // NBUF*2*32
    const size_t off_st2 = off_st1 + NBUF * 2 * 32;           // NBUF*2*64

    (void)hipMemsetAsync(ws + off_st0, 0, (size_t)(NBUF * 2 * (16 + 32 + 64)) * sizeof(float), stream);

    // stage 0: cast data -> bf16 table (4MB, L2-resident), conv at request floor
    cast_bf16_kernel<<<N6 / 256, 256, 0, stream>>>(
        (const f32x4*)data, (u32x2*)(ws + off_xb0), N6);
    conv0_kernel<<<N6 / 256, 256, 0, stream>>>(
        (const unsigned long long*)(ws + off_xb0), neigh0, W0,
        (unsigned*)(ws + off_y0), ws + off_st0);
    pool_fin0_kernel<<<(N5 * 8) / 256, 256, 0, stream>>>(
        (const unsigned*)(ws + off_y0), ws + off_st0, g0, b0,
        (unsigned*)(ws + off_xb1), 1.f / N6, N5 * 8);

    // stage 1: proven 2-pass conv, bf16 y1
    conv1_kernel<<<dim3(N5 / 256, 2), 256, 0, stream>>>(
        (const u32x4*)(ws + off_xb1), neigh1, W1,
        (unsigned*)(ws + off_y1), ws + off_st1);
    pool_fin1_kernel<<<(N4 * 16) / 256, 256, 0, stream>>>(
        (const unsigned*)(ws + off_y1), ws + off_st1, g1, b1,
        (unsigned*)(ws + off_xb2), 1.f / N5, N4 * 16);

    // stage 2 + fused pool/BN/scatter epilogue (full coverage, no memset)
    conv2_kernel<<<N4 / 16, 256, 0, stream>>>(
        (const u32x4*)(ws + off_xb2), neigh2, W2,
        (unsigned*)(ws + off_y2), ws + off_st2);
    pool_fin2_scatter_kernel<<<(N3 * 32) / 256, 256, 0, stream>>>(
        (const unsigned*)(ws + off_y2), ws + off_st2, g2, b2,
        vox, (float*)d_out, 1.f / N4);
}

// Round 16
// 239.272 us; speedup vs baseline: 1.0446x; 1.0446x over previous
//
#include <hip/hip_runtime.h>

#define BN_EPS 1e-5f
#define NBUF 64   // spread buffers for stat atomics

typedef float        f32x4 __attribute__((ext_vector_type(4)));
typedef float        f32x2 __attribute__((ext_vector_type(2)));
typedef unsigned int u32x2 __attribute__((ext_vector_type(2)));
typedef unsigned int u32x4 __attribute__((ext_vector_type(4)));

__device__ inline unsigned pack_bf16(float a, float b) {
    unsigned ua = __float_as_uint(a);
    unsigned ub = __float_as_uint(b);
    ua = (ua + 0x7fffu + ((ua >> 16) & 1u)) >> 16;
    ub = (ub + 0x7fffu + ((ub >> 16) & 1u)) >> 16;
    return ua | (ub << 16);
}
__device__ inline float bf_lo(unsigned u) { return __uint_as_float(u << 16); }
__device__ inline float bf_hi(unsigned u) { return __uint_as_float(u & 0xffff0000u); }

// ---------------------------------------------------------------------------
// Cast fp32 -> packed bf16 (RNE). One thread = 4 floats -> 2 uints.
// ---------------------------------------------------------------------------
__global__ void __launch_bounds__(256) cast_bf16_kernel(
    const f32x4* __restrict__ in, u32x2* __restrict__ out, int n4)
{
    const int t = blockIdx.x * 256 + threadIdx.x;
    if (t >= n4) return;
    const f32x4 v = in[t];
    u32x2 r;
    r.x = pack_bf16(v.x, v.y);
    r.y = pack_bf16(v.z, v.w);
    out[t] = r;
}

// ---------------------------------------------------------------------------
// Stage 0 (round-8 proven body, 84 VGPR, request-rate floor ~121us).
// idx: PLAIN coalesced global->LDS staging, stride-27 read.
// Gathers: all 27 in flight, agent-scope relaxed (L1 bypass, L2-resident 4MB).
// W: LDS broadcast. y0 stored as PACKED BF16 (8 u32/node = 16MB).
// ---------------------------------------------------------------------------
__global__ void __launch_bounds__(256) conv0_kernel(
    const unsigned long long* __restrict__ xb, const int* __restrict__ neigh,
    const float* __restrict__ W, unsigned* __restrict__ y,
    float* __restrict__ stats)
{
    __shared__ int   idxlds[256 * 27];
    __shared__ float Wlds[27 * 4 * 16];

    for (int i = threadIdx.x; i < 27 * 4 * 16; i += 256) Wlds[i] = W[i];
    {
        const size_t base = (size_t)blockIdx.x * (256 * 27);
        for (int i = threadIdx.x; i < 256 * 27; i += 256)
            idxlds[i] = neigh[base + i];
    }
    __syncthreads();

    const int node = blockIdx.x * 256 + threadIdx.x;

    unsigned long long xr[27];
#pragma unroll
    for (int j = 0; j < 27; ++j) {
        const int nb = idxlds[threadIdx.x * 27 + j];
        xr[j] = __hip_atomic_load(xb + nb, __ATOMIC_RELAXED,
                                  __HIP_MEMORY_SCOPE_AGENT);
    }

    float acc[16];
#pragma unroll
    for (int c = 0; c < 16; ++c) acc[c] = 0.f;

#pragma unroll
    for (int j = 0; j < 27; ++j) {
        const unsigned lo = (unsigned)xr[j];
        const unsigned hi = (unsigned)(xr[j] >> 32);
        float xv[4];
        xv[0] = bf_lo(lo); xv[1] = bf_hi(lo);
        xv[2] = bf_lo(hi); xv[3] = bf_hi(hi);
#pragma unroll
        for (int kk = 0; kk < 4; ++kk) {
            const f32x4* wv = (const f32x4*)&Wlds[(j * 4 + kk) * 16];
#pragma unroll
            for (int c4 = 0; c4 < 4; ++c4) {
                const f32x4 w = wv[c4];
                acc[c4 * 4 + 0] = fmaf(xv[kk], w.x, acc[c4 * 4 + 0]);
                acc[c4 * 4 + 1] = fmaf(xv[kk], w.y, acc[c4 * 4 + 1]);
                acc[c4 * 4 + 2] = fmaf(xv[kk], w.z, acc[c4 * 4 + 2]);
                acc[c4 * 4 + 3] = fmaf(xv[kk], w.w, acc[c4 * 4 + 3]);
            }
        }
    }

    // y0 as packed bf16: 8 u32 per node (stats below stay fp32-exact)
    {
        unsigned* yr = y + (size_t)node * 8;
        u32x4 w0, w1;
        w0.x = pack_bf16(acc[0],  acc[1]);   w0.y = pack_bf16(acc[2],  acc[3]);
        w0.z = pack_bf16(acc[4],  acc[5]);   w0.w = pack_bf16(acc[6],  acc[7]);
        w1.x = pack_bf16(acc[8],  acc[9]);   w1.y = pack_bf16(acc[10], acc[11]);
        w1.z = pack_bf16(acc[12], acc[13]);  w1.w = pack_bf16(acc[14], acc[15]);
        __builtin_nontemporal_store(w0, (u32x4*)yr);
        __builtin_nontemporal_store(w1, (u32x4*)(yr + 4));
    }

    float* buf = stats + (blockIdx.x & (NBUF - 1)) * (2 * 16);
#pragma unroll
    for (int c = 0; c < 16; ++c) {
        float v = acc[c];
        float q = v * v;
#pragma unroll
        for (int off = 32; off > 0; off >>= 1) {
            v += __shfl_xor(v, off, 64);
            q += __shfl_xor(q, off, 64);
        }
        if ((threadIdx.x & 63) == 0) {
            atomicAdd(&buf[c], v);
            atomicAdd(&buf[16 + c], q);
        }
    }
}

// ---------------------------------------------------------------------------
// Stage-0 pool-finalize from bf16 y0: BN fold + affine + ReLU + 8-sibling
// maxpool + bf16 pack. thread t -> (parent p, channel pair).
// ---------------------------------------------------------------------------
__global__ void __launch_bounds__(256) pool_fin0_kernel(
    const unsigned* __restrict__ y, const float* __restrict__ stats,
    const float* __restrict__ gamma, const float* __restrict__ beta,
    unsigned* __restrict__ xout, float invN, int total2)
{
    __shared__ float ss[32];
    if (threadIdx.x < 16) {
        const int c = threadIdx.x;
        float s = 0.f, q = 0.f;
        for (int b = 0; b < NBUF; ++b) {
            s += stats[b * 32 + c];
            q += stats[b * 32 + 16 + c];
        }
        const float mean = s * invN;
        const float var  = fmaf(-mean, mean, q * invN);
        const float sc   = gamma[c] * rsqrtf(var + BN_EPS);
        ss[c]      = sc;
        ss[16 + c] = fmaf(-mean, sc, beta[c]);
    }
    __syncthreads();

    const int t = blockIdx.x * 256 + threadIdx.x;
    if (t >= total2) return;
    const int p    = t >> 3;       // parent
    const int pair = t & 7;        // channel pair (c = 2*pair, 2*pair+1)
    const int c2 = pair * 2;
    const float sc0 = ss[c2],     sh0 = ss[16 + c2];
    const float sc1 = ss[c2 + 1], sh1 = ss[16 + c2 + 1];
    const unsigned* yr = y + (size_t)p * 64 + pair;   // 8 siblings * 8 u32
    float m0 = -3.4e38f, m1 = -3.4e38f;
#pragma unroll
    for (int i = 0; i < 8; ++i) {
        const unsigned u = __builtin_nontemporal_load(yr + i * 8);
        m0 = fmaxf(m0, fmaf(bf_lo(u), sc0, sh0));
        m1 = fmaxf(m1, fmaf(bf_hi(u), sc1, sh1));
    }
    m0 = fmaxf(m0, 0.f);
    m1 = fmaxf(m1, 0.f);
    xout[t] = pack_bf16(m0, m1);
}

// ---------------------------------------------------------------------------
// Stage 1 (round-8 proven 2-pass shape): W tile 16 in LDS (27.6KB),
// grid (N5/256, 2), plain idx preload, GRP=3 gather staging. y1 fp32.
// ---------------------------------------------------------------------------
__global__ void __launch_bounds__(256) conv1_kernel(
    const u32x4* __restrict__ xb, const int* __restrict__ neigh,
    const float* __restrict__ W, float* __restrict__ y,
    float* __restrict__ stats)
{
    __shared__ float Wlds[27 * 16 * 16];
    const int cobase = blockIdx.y * 16;

    for (int i = threadIdx.x; i < 27 * 16 * 16; i += 256) {
        int k = i >> 4, c = i & 15;
        Wlds[i] = W[k * 32 + cobase + c];
    }
    __syncthreads();

    const int node = blockIdx.x * 256 + threadIdx.x;
    const int* nrow = neigh + (size_t)node * 27;

    int idx[27];
#pragma unroll
    for (int j = 0; j < 27; ++j) idx[j] = nrow[j];

    float acc[16];
#pragma unroll
    for (int c = 0; c < 16; ++c) acc[c] = 0.f;

#pragma unroll 1
    for (int g = 0; g < 27; g += 3) {
        u32x4 xa[3], xc[3];
#pragma unroll
        for (int u = 0; u < 3; ++u) {
            const size_t r = (size_t)idx[g + u] * 2;
            xa[u] = xb[r];
            xc[u] = xb[r + 1];
        }
#pragma unroll
        for (int u = 0; u < 3; ++u) {
            const int j = g + u;
            float xv[16];
            xv[0]  = bf_lo(xa[u].x); xv[1]  = bf_hi(xa[u].x);
            xv[2]  = bf_lo(xa[u].y); xv[3]  = bf_hi(xa[u].y);
            xv[4]  = bf_lo(xa[u].z); xv[5]  = bf_hi(xa[u].z);
            xv[6]  = bf_lo(xa[u].w); xv[7]  = bf_hi(xa[u].w);
            xv[8]  = bf_lo(xc[u].x); xv[9]  = bf_hi(xc[u].x);
            xv[10] = bf_lo(xc[u].y); xv[11] = bf_hi(xc[u].y);
            xv[12] = bf_lo(xc[u].z); xv[13] = bf_hi(xc[u].z);
            xv[14] = bf_lo(xc[u].w); xv[15] = bf_hi(xc[u].w);
#pragma unroll
            for (int k = 0; k < 16; ++k) {
                const f32x4* wv = (const f32x4*)&Wlds[(j * 16 + k) * 16];
#pragma unroll
                for (int c4 = 0; c4 < 4; ++c4) {
                    const f32x4 w = wv[c4];
                    acc[c4 * 4 + 0] = fmaf(xv[k], w.x, acc[c4 * 4 + 0]);
                    acc[c4 * 4 + 1] = fmaf(xv[k], w.y, acc[c4 * 4 + 1]);
                    acc[c4 * 4 + 2] = fmaf(xv[k], w.z, acc[c4 * 4 + 2]);
                    acc[c4 * 4 + 3] = fmaf(xv[k], w.w, acc[c4 * 4 + 3]);
                }
            }
        }
    }

    f32x4* yr = (f32x4*)(y + (size_t)node * 32 + cobase);
#pragma unroll
    for (int c4 = 0; c4 < 4; ++c4) {
        f32x4 v = { acc[c4 * 4 + 0], acc[c4 * 4 + 1], acc[c4 * 4 + 2], acc[c4 * 4 + 3] };
        __builtin_nontemporal_store(v, yr + c4);
    }

    float* buf = stats + (blockIdx.x & (NBUF - 1)) * (2 * 32);
#pragma unroll
    for (int c = 0; c < 16; ++c) {
        float v = acc[c];
        float q = v * v;
#pragma unroll
        for (int off = 32; off > 0; off >>= 1) {
            v += __shfl_xor(v, off, 64);
            q += __shfl_xor(q, off, 64);
        }
        if ((threadIdx.x & 63) == 0) {
            atomicAdd(&buf[cobase + c], v);
            atomicAdd(&buf[32 + cobase + c], q);
        }
    }
}

// ---------------------------------------------------------------------------
// Fused BN-finalize + affine + ReLU + 8-sibling maxpool (stage 1, fp32 y).
// ---------------------------------------------------------------------------
template<int COUT>
__global__ void __launch_bounds__(256) pool_fin_kernel(
    const float* __restrict__ y, const float* __restrict__ stats,
    const float* __restrict__ gamma, const float* __restrict__ beta,
    unsigned* __restrict__ xout, float invN, int total2)
{
    __shared__ float ss[2 * COUT];
    if (threadIdx.x < COUT) {
        const int c = threadIdx.x;
        float s = 0.f, q = 0.f;
        for (int b = 0; b < NBUF; ++b) {
            s += stats[b * 2 * COUT + c];
            q += stats[b * 2 * COUT + COUT + c];
        }
        const float mean = s * invN;
        const float var  = fmaf(-mean, mean, q * invN);
        const float sc   = gamma[c] * rsqrtf(var + BN_EPS);
        ss[c]        = sc;
        ss[COUT + c] = fmaf(-mean, sc, beta[c]);
    }
    __syncthreads();

    const int t = blockIdx.x * 256 + threadIdx.x;
    if (t >= total2) return;
    const int p  = t / (COUT / 2);
    const int c2 = (t % (COUT / 2)) * 2;
    const float sc0 = ss[c2],     sh0 = ss[COUT + c2];
    const float sc1 = ss[c2 + 1], sh1 = ss[COUT + c2 + 1];
    const float* yr = y + (size_t)p * 8 * COUT + c2;
    float m0 = -3.4e38f, m1 = -3.4e38f;
#pragma unroll
    for (int i = 0; i < 8; ++i) {
        const f32x2 v = __builtin_nontemporal_load((const f32x2*)(yr + i * COUT));
        m0 = fmaxf(m0, fmaf(v.x, sc0, sh0));
        m1 = fmaxf(m1, fmaf(v.y, sc1, sh1));
    }
    m0 = fmaxf(m0, 0.f);
    m1 = fmaxf(m1, 0.f);
    xout[t] = pack_bf16(m0, m1);
}

// ---------------------------------------------------------------------------
// Stage 2: round-8 shape. thread-per-(node, channel-quad), 16 nodes/block,
// idx in LDS, W fp32 straight from L2. y2 fp32.
// ---------------------------------------------------------------------------
__global__ void __launch_bounds__(256) conv2_kernel(
    const u32x4* __restrict__ xb, const int* __restrict__ neigh,
    const float* __restrict__ W, float* __restrict__ y,
    float* __restrict__ stats)
{
    __shared__ int idxlds[16 * 27];
    const int nbase = blockIdx.x * 16;
    for (int i = threadIdx.x; i < 16 * 27; i += 256) {
        int n = i / 27, j = i - n * 27;
        idxlds[i] = neigh[(size_t)(nbase + n) * 27 + j];
    }
    __syncthreads();

    const int ln = threadIdx.x >> 4;
    const int c4 = threadIdx.x & 15;
    const int node = nbase + ln;

    f32x4 acc = { 0.f, 0.f, 0.f, 0.f };

#pragma unroll 1
    for (int j = 0; j < 27; ++j) {
        const int nb = idxlds[ln * 27 + j];
        const u32x4* xr = xb + (size_t)nb * 4;
        u32x4 xq[4];
#pragma unroll
        for (int q = 0; q < 4; ++q) xq[q] = xr[q];
#pragma unroll
        for (int q = 0; q < 4; ++q) {
            float xv[8];
            xv[0] = bf_lo(xq[q].x); xv[1] = bf_hi(xq[q].x);
            xv[2] = bf_lo(xq[q].y); xv[3] = bf_hi(xq[q].y);
            xv[4] = bf_lo(xq[q].z); xv[5] = bf_hi(xq[q].z);
            xv[6] = bf_lo(xq[q].w); xv[7] = bf_hi(xq[q].w);
#pragma unroll
            for (int h = 0; h < 8; ++h) {
                const int k = q * 8 + h;
                const f32x4 w = *(const f32x4*)(W + ((size_t)j * 32 + k) * 64 + c4 * 4);
                acc.x = fmaf(xv[h], w.x, acc.x);
                acc.y = fmaf(xv[h], w.y, acc.y);
                acc.z = fmaf(xv[h], w.z, acc.z);
                acc.w = fmaf(xv[h], w.w, acc.w);
            }
        }
    }

    __builtin_nontemporal_store(acc, (f32x4*)(y + (size_t)node * 64 + c4 * 4));

    float sx = acc.x, sy = acc.y, sz = acc.z, sw = acc.w;
    float qx = acc.x * acc.x, qy = acc.y * acc.y, qz = acc.z * acc.z, qw = acc.w * acc.w;
#pragma unroll
    for (int off = 16; off <= 32; off <<= 1) {
        sx += __shfl_xor(sx, off, 64);  sy += __shfl_xor(sy, off, 64);
        sz += __shfl_xor(sz, off, 64);  sw += __shfl_xor(sw, off, 64);
        qx += __shfl_xor(qx, off, 64);  qy += __shfl_xor(qy, off, 64);
        qz += __shfl_xor(qz, off, 64);  qw += __shfl_xor(qw, off, 64);
    }
    if ((threadIdx.x & 63) < 16) {
        float* buf = stats + (blockIdx.x & (NBUF - 1)) * (2 * 64);
        atomicAdd(&buf[c4 * 4 + 0], sx);
        atomicAdd(&buf[c4 * 4 + 1], sy);
        atomicAdd(&buf[c4 * 4 + 2], sz);
        atomicAdd(&buf[c4 * 4 + 3], sw);
        atomicAdd(&buf[64 + c4 * 4 + 0], qx);
        atomicAdd(&buf[64 + c4 * 4 + 1], qy);
        atomicAdd(&buf[64 + c4 * 4 + 2], qz);
        atomicAdd(&buf[64 + c4 * 4 + 3], qw);
    }
}

// ---------------------------------------------------------------------------
// Stage-2 epilogue: BN-finalize + affine + ReLU + maxpool + octree2voxel
// scatter fused. vox = arange(N3) covers every output element -> no memset.
// ---------------------------------------------------------------------------
__global__ void __launch_bounds__(256) pool_fin2_scatter_kernel(
    const float* __restrict__ y, const float* __restrict__ stats,
    const float* __restrict__ gamma, const float* __restrict__ beta,
    const int* __restrict__ vox, float* __restrict__ out, float invN)
{
    __shared__ float ss[128];
    if (threadIdx.x < 64) {
        const int c = threadIdx.x;
        float s = 0.f, q = 0.f;
        for (int b = 0; b < NBUF; ++b) {
            s += stats[b * 128 + c];
            q += stats[b * 128 + 64 + c];
        }
        const float mean = s * invN;
        const float var  = fmaf(-mean, mean, q * invN);
        const float sc   = gamma[c] * rsqrtf(var + BN_EPS);
        ss[c]      = sc;
        ss[64 + c] = fmaf(-mean, sc, beta[c]);
    }
    __syncthreads();

    const int t = blockIdx.x * 256 + threadIdx.x;   // N3*32 = 32768 threads
    const int p  = t >> 5;
    const int c2 = (t & 31) * 2;
    const float sc0 = ss[c2],     sh0 = ss[64 + c2];
    const float sc1 = ss[c2 + 1], sh1 = ss[64 + c2 + 1];
    const float* yr = y + (size_t)p * 8 * 64 + c2;
    float m0 = -3.4e38f, m1 = -3.4e38f;
#pragma unroll
    for (int i = 0; i < 8; ++i) {
        const f32x2 v = __builtin_nontemporal_load((const f32x2*)(yr + i * 64));
        m0 = fmaxf(m0, fmaf(v.x, sc0, sh0));
        m1 = fmaxf(m1, fmaf(v.y, sc1, sh1));
    }
    m0 = fmaxf(m0, 0.f);
    m1 = fmaxf(m1, 0.f);

    const int r = vox[p];
    const int base = ((r >> 9) << 15) + (r & 511);
    out[base + (c2 << 9)]       = m0;
    out[base + ((c2 + 1) << 9)] = m1;
}

extern "C" void kernel_launch(void* const* d_in, const int* in_sizes, int n_in,
                              void* d_out, int out_size, void* d_ws, size_t ws_size,
                              hipStream_t stream)
{
    const float* data = (const float*)d_in[0];
    const float* W0   = (const float*)d_in[1];
    const float* g0   = (const float*)d_in[2];
    const float* b0   = (const float*)d_in[3];
    const float* W1   = (const float*)d_in[4];
    const float* g1   = (const float*)d_in[5];
    const float* b1   = (const float*)d_in[6];
    const float* W2   = (const float*)d_in[7];
    const float* g2   = (const float*)d_in[8];
    const float* b2   = (const float*)d_in[9];
    const int* neigh0 = (const int*)d_in[10];
    const int* neigh1 = (const int*)d_in[11];
    const int* neigh2 = (const int*)d_in[12];
    const int* vox    = (const int*)d_in[13];

    const int N6 = 524288, N5 = 65536, N4 = 8192, N3 = 1024;

    float* ws = (float*)d_ws;
    const size_t off_y0  = 0;                                 // N6*8  (bf16 y0, u32)
    const size_t off_xb1 = off_y0 + (size_t)N6 * 8;           // N5*8  (bf16 x1)
    const size_t off_y1  = off_xb1 + (size_t)N5 * 8;          // N5*32
    const size_t off_xb0 = off_y1;                            // N6*2  (bf16 x0, alias)
    const size_t off_xb2 = off_y1 + (size_t)N5 * 32;          // N4*16 (bf16 x2)
    const size_t off_y2  = off_xb2 + (size_t)N4 * 16;         // N4*64
    const size_t off_st0 = off_y2 + (size_t)N4 * 64;          // NBUF*2*16
    const size_t off_st1 = off_st0 + NBUF * 2 * 16;           // NBUF*2*32
    const size_t off_st2 = off_st1 + NBUF * 2 * 32;           // NBUF*2*64

    (void)hipMemsetAsync(ws + off_st0, 0, (size_t)(NBUF * 2 * (16 + 32 + 64)) * sizeof(float), stream);

    // stage 0: cast data -> bf16 table (4MB, L2-resident), conv at request floor
    cast_bf16_kernel<<<N6 / 256, 256, 0, stream>>>(
        (const f32x4*)data, (u32x2*)(ws + off_xb0), N6);
    conv0_kernel<<<N6 / 256, 256, 0, stream>>>(
        (const unsigned long long*)(ws + off_xb0), neigh0, W0,
        (unsigned*)(ws + off_y0), ws + off_st0);
    pool_fin0_kernel<<<(N5 * 8) / 256, 256, 0, stream>>>(
        (const unsigned*)(ws + off_y0), ws + off_st0, g0, b0,
        (unsigned*)(ws + off_xb1), 1.f / N6, N5 * 8);

    // stage 1: proven 2-pass conv
    conv1_kernel<<<dim3(N5 / 256, 2), 256, 0, stream>>>(
        (const u32x4*)(ws + off_xb1), neigh1, W1, ws + off_y1, ws + off_st1);
    pool_fin_kernel<32><<<(N4 * 16) / 256, 256, 0, stream>>>(
        ws + off_y1, ws + off_st1, g1, b1,
        (unsigned*)(ws + off_xb2), 1.f / N5, N4 * 16);

    // stage 2 + fused pool/BN/scatter epilogue (full coverage, no memset)
    conv2_kernel<<<N4 / 16, 256, 0, stream>>>(
        (const u32x4*)(ws + off_xb2), neigh2, W2, ws + off_y2, ws + off_st2);
    pool_fin2_scatter_kernel<<<(N3 * 32) / 256, 256, 0, stream>>>(
        ws + off_y2, ws + off_st2, g2, b2, vox, (float*)d_out, 1.f / N4);
}